// Round 1
// baseline (44345.139 us; speedup 1.0000x reference)
//
#include <hip/hip_runtime.h>

#define CDIV(a,b) (((a)+(b)-1)/(b))
#define TS 16

// ---------------- direct convolution, fused ReLU + input scale ----------------
__global__ void conv2d_relu_kernel(
    const float* __restrict__ in, const float* __restrict__ wt,
    const float* __restrict__ bs, float* __restrict__ out,
    int N, int Cin, int Hin, int Win,
    int Cout, int K, int stride, int pad, int groups,
    int Hout, int Wout, float inscale)
{
    int idx = blockIdx.x * blockDim.x + threadIdx.x;
    int total = N * Cout * Hout * Wout;
    if (idx >= total) return;
    int wo = idx % Wout; int t = idx / Wout;
    int ho = t % Hout; t /= Hout;
    int co = t % Cout; int n = t / Cout;
    int cig = Cin / groups;
    int cog = Cout / groups;
    int g = co / cog;
    const float* wrow = wt + (size_t)co * cig * K * K;
    const float* inb  = in + ((size_t)n * Cin + (size_t)g * cig) * Hin * Win;
    float acc = 0.f;
    int hi0 = ho * stride - pad, wi0 = wo * stride - pad;
    for (int ci = 0; ci < cig; ++ci) {
        const float* ip = inb + (size_t)ci * Hin * Win;
        const float* wp = wrow + (size_t)ci * K * K;
        for (int kh = 0; kh < K; ++kh) {
            int hi = hi0 + kh;
            if ((unsigned)hi >= (unsigned)Hin) continue;
            for (int kw = 0; kw < K; ++kw) {
                int wi = wi0 + kw;
                if ((unsigned)wi >= (unsigned)Win) continue;
                acc += ip[hi * Win + wi] * wp[kh * K + kw];
            }
        }
    }
    float v = bs[co] + inscale * acc;
    out[idx] = fmaxf(v, 0.f);
}

// ---------------- maxpool 3x3 stride 2 (all windows in-range for 55/27/13) ----
__global__ void maxpool3s2_kernel(const float* __restrict__ in, float* __restrict__ out,
                                  int N, int C, int Hin, int Win, int Hout, int Wout)
{
    int idx = blockIdx.x * blockDim.x + threadIdx.x;
    int total = N * C * Hout * Wout;
    if (idx >= total) return;
    int wo = idx % Wout; int t = idx / Wout;
    int ho = t % Hout; t /= Hout;
    int c = t % C; int n = t / C;
    const float* ip = in + ((size_t)n * C + c) * Hin * Win;
    int h0 = ho * 2, w0 = wo * 2;
    float m = -1e30f;
    for (int dh = 0; dh < 3; ++dh)
        for (int dw = 0; dw < 3; ++dw)
            m = fmaxf(m, ip[(h0 + dh) * Win + (w0 + dw)]);
    out[idx] = m;
}

// ---------------- LRN (n=5, alpha=1e-4, beta=0.75, k=1) in-place --------------
// One thread per (n, h, w): slides a 5-wide channel window with a register ring.
__global__ void lrn_inplace_kernel(float* __restrict__ x, int N, int C, int HW)
{
    int idx = blockIdx.x * blockDim.x + threadIdx.x;
    int total = N * HW;
    if (idx >= total) return;
    int p = idx % HW; int n = idx / HW;
    float* base = x + (size_t)n * C * HW + p;
    const float an = 1e-4f / 5.f;
    float r0 = 0.f, r1 = 0.f, r2, r3, r4;
    r2 = base[0];
    r3 = (C > 1) ? base[(size_t)HW] : 0.f;
    r4 = (C > 2) ? base[(size_t)2 * HW] : 0.f;
    float s = r2 * r2 + r3 * r3 + r4 * r4;
    for (int c = 0; c < C; ++c) {
        base[(size_t)c * HW] = r2 / powf(1.f + an * s, 0.75f);
        s -= r0 * r0;
        r0 = r1; r1 = r2; r2 = r3; r3 = r4;
        r4 = (c + 3 < C) ? base[(size_t)(c + 3) * HW] : 0.f;
        s += r4 * r4;
    }
}

// ---------------- GEMM: out[M,N] = A[M,K] @ W[N,K]^T (+bias) (+relu) ----------
__global__ void gemm_nt_kernel(const float* __restrict__ A, const float* __restrict__ W,
                               const float* __restrict__ bias, float* __restrict__ out,
                               int M, int N, int Kd, int relu)
{
    __shared__ float As[TS][TS + 1], Ws[TS][TS + 1];
    int tx = threadIdx.x, ty = threadIdx.y;
    int row = blockIdx.y * TS + ty;        // m
    int col = blockIdx.x * TS + tx;        // n
    int wrow = blockIdx.x * TS + ty;
    float acc = 0.f;
    for (int k0 = 0; k0 < Kd; k0 += TS) {
        As[ty][tx] = (row < M && k0 + tx < Kd) ? A[(size_t)row * Kd + k0 + tx] : 0.f;
        Ws[ty][tx] = (wrow < N && k0 + tx < Kd) ? W[(size_t)wrow * Kd + k0 + tx] : 0.f;
        __syncthreads();
        for (int kk = 0; kk < TS; ++kk) acc += As[ty][kk] * Ws[tx][kk];
        __syncthreads();
    }
    if (row < M && col < N) {
        float v = acc + (bias ? bias[col] : 0.f);
        out[(size_t)row * N + col] = relu ? fmaxf(v, 0.f) : v;
    }
}

// ---------------- GEMM: out[M,N] = A[M,K] @ W[K,N] ----------------------------
__global__ void gemm_nn_kernel(const float* __restrict__ A, const float* __restrict__ W,
                               float* __restrict__ out, int M, int N, int Kd)
{
    __shared__ float As[TS][TS + 1], Ws[TS][TS + 1];
    int tx = threadIdx.x, ty = threadIdx.y;
    int row = blockIdx.y * TS + ty;
    int col = blockIdx.x * TS + tx;
    float acc = 0.f;
    for (int k0 = 0; k0 < Kd; k0 += TS) {
        As[ty][tx] = (row < M && k0 + tx < Kd) ? A[(size_t)row * Kd + k0 + tx] : 0.f;
        Ws[ty][tx] = (k0 + ty < Kd && col < N) ? W[(size_t)(k0 + ty) * N + col] : 0.f;
        __syncthreads();
        for (int kk = 0; kk < TS; ++kk) acc += As[ty][kk] * Ws[kk][tx];
        __syncthreads();
    }
    if (row < M && col < N) out[(size_t)row * N + col] = acc;
}

// ---------------- backward helpers --------------------------------------------
__global__ void g2m_kernel(const float* __restrict__ wc, const int* __restrict__ gt,
                           const float* __restrict__ h2, float* __restrict__ g2m,
                           int B, int D)
{
    int idx = blockIdx.x * blockDim.x + threadIdx.x;
    if (idx >= B * D) return;
    int b = idx / D, i = idx % D;
    g2m[idx] = (h2[idx] > 0.f) ? wc[(size_t)gt[b] * D + i] : 0.f;
}

__global__ void relumask_kernel(float* __restrict__ g, const float* __restrict__ h, int n)
{
    int idx = blockIdx.x * blockDim.x + threadIdx.x;
    if (idx >= n) return;
    if (h[idx] <= 0.f) g[idx] = 0.f;
}

__global__ void spatial_mean_kernel(const float* __restrict__ gf, float* __restrict__ sm,
                                    int B, int C, int HW)
{
    int idx = blockIdx.x * blockDim.x + threadIdx.x;
    if (idx >= B * HW) return;
    int b = idx / HW, p = idx % HW;
    const float* g = gf + (size_t)b * C * HW + p;
    float s = 0.f;
    for (int c = 0; c < C; ++c) s += g[(size_t)c * HW];
    sm[idx] = s / (float)C;
}

// ---------------- RSC spatial mask: exact JAX semantics ------------------------
// th = value at descending-sort index `drop` (duplicate-aware rank select);
// candidates sm>=th; sc = cand ? u : -1; top-`drop` of sc (ties -> lowest index).
__global__ void rsc_mask_kernel(const float* __restrict__ sm, const float* __restrict__ u,
                                float* __restrict__ mask, int B, int HW, int drop)
{
    int b = blockIdx.x * blockDim.x + threadIdx.x;
    if (b >= B) return;
    const float* s = sm + (size_t)b * HW;
    const float* uu = u + (size_t)b * HW;
    float th = 0.f;
    for (int p = 0; p < HW; ++p) {
        float v = s[p];
        int cg = 0, ce = 0;
        for (int q = 0; q < HW; ++q) { cg += (s[q] > v); ce += (s[q] == v); }
        if (cg <= drop && drop < cg + ce) { th = v; break; }
    }
    float sc[36];
    bool chosen[36];
    for (int p = 0; p < HW; ++p) { sc[p] = (s[p] >= th) ? uu[p] : -1.0f; chosen[p] = false; }
    for (int r = 0; r < drop; ++r) {
        int best = 0; float bv = -1e30f;
        for (int p = 0; p < HW; ++p)
            if (!chosen[p] && sc[p] > bv) { bv = sc[p]; best = p; }
        chosen[best] = true;
    }
    float* m = mask + (size_t)b * HW;
    for (int p = 0; p < HW; ++p) m[p] = chosen[p] ? 0.f : 1.f;
}

__global__ void maskfeat_kernel(const float* __restrict__ feat, const float* __restrict__ mask,
                                float* __restrict__ featb, int B, int CHW, int HW)
{
    int idx = blockIdx.x * blockDim.x + threadIdx.x;
    if (idx >= B * CHW) return;
    int b = idx / CHW, j = idx % CHW;
    featb[idx] = feat[idx] * mask[(size_t)b * HW + (j % HW)];
}

__global__ void cv_kernel(const float* __restrict__ out0, const float* __restrict__ out1,
                          const int* __restrict__ gt, float* __restrict__ cv, int B, int NCc)
{
    int b = blockIdx.x * blockDim.x + threadIdx.x;
    if (b >= B) return;
    const float* a = out0 + (size_t)b * NCc;
    const float* c = out1 + (size_t)b * NCc;
    int g = gt[b];
    float m0 = -1e30f, m1 = -1e30f;
    for (int i = 0; i < NCc; ++i) { m0 = fmaxf(m0, a[i]); m1 = fmaxf(m1, c[i]); }
    float s0 = 0.f, s1 = 0.f;
    for (int i = 0; i < NCc; ++i) { s0 += expf(a[i] - m0); s1 += expf(c[i] - m1); }
    float pb = expf(a[g] - m0) / s0;
    float pa = expf(c[g] - m1) / s1;
    cv[b] = fmaxf(pb - pa - 1e-4f, 0.f);
}

// th_fg = cv value at descending-sort index kidx (duplicate-aware);
// keep = !(cv > th_fg); out row = keep ? out0 : out1 (flag==0 -> out0).
__global__ void final_select_kernel(const float* __restrict__ cv, const float* __restrict__ out0,
                                    const float* __restrict__ out1, const int* __restrict__ flag,
                                    float* __restrict__ out, int B, int NCc, int kidx)
{
    __shared__ float thfg;
    int b = threadIdx.x;
    float v = cv[b];
    int cg = 0, ce = 0;
    for (int j = 0; j < B; ++j) { float w = cv[j]; cg += (w > v); ce += (w == v); }
    if (cg <= kidx && kidx < cg + ce) thfg = v;
    __syncthreads();
    bool keep = !(v > thfg);
    if (*flag == 0) keep = true;
    const float* src = keep ? out0 : out1;
    for (int c = 0; c < NCc; ++c)
        out[(size_t)b * NCc + c] = src[(size_t)b * NCc + c];
}

// ------------------------------------------------------------------------------
extern "C" void kernel_launch(void* const* d_in, const int* in_sizes, int n_in,
                              void* d_out, int out_size, void* d_ws, size_t ws_size,
                              hipStream_t stream) {
    const float* x   = (const float*)d_in[0];
    const int*   gt  = (const int*)d_in[1];
    const float* u   = (const float*)d_in[2];
    const int*   flag= (const int*)d_in[3];
    const float* w1  = (const float*)d_in[4];  const float* b1 = (const float*)d_in[5];
    const float* w2  = (const float*)d_in[6];  const float* b2 = (const float*)d_in[7];
    const float* w3  = (const float*)d_in[8];  const float* b3 = (const float*)d_in[9];
    const float* w4  = (const float*)d_in[10]; const float* b4 = (const float*)d_in[11];
    const float* w5  = (const float*)d_in[12]; const float* b5 = (const float*)d_in[13];
    const float* w6  = (const float*)d_in[14]; const float* b6 = (const float*)d_in[15];
    const float* w7  = (const float*)d_in[16]; const float* b7 = (const float*)d_in[17];
    const float* wc  = (const float*)d_in[18]; const float* bc = (const float*)d_in[19];
    float* out = (float*)d_out;

    // ---- workspace layout (floats), ~170 MB total ----
    float* w = (float*)d_ws;
    size_t off = 0;
    auto alloc = [&](size_t n) { float* p = w + off; off += n; return p; };
    float* feat  = alloc((size_t)128 * 9216);
    float* featb = alloc((size_t)128 * 9216);
    float* h1    = alloc((size_t)128 * 4096);
    float* h2    = alloc((size_t)128 * 4096);
    float* h1b   = alloc((size_t)128 * 4096);
    float* h2b   = alloc((size_t)128 * 4096);
    float* g1    = alloc((size_t)128 * 4096);
    float* g2m   = alloc((size_t)128 * 4096);
    float* gf    = alloc((size_t)128 * 9216);
    float* out0  = alloc((size_t)128 * 100);
    float* out1  = alloc((size_t)128 * 100);
    float* sm    = alloc((size_t)128 * 36);
    float* mask  = alloc((size_t)128 * 36);
    float* cv    = alloc(128);
    float* cbuf  = alloc((size_t)16 * 96 * 55 * 55);           // conv1/conv2 chunk buffer
    float* p1    = alloc((size_t)128 * 96 * 27 * 27);
    float* p2    = alloc((size_t)128 * 256 * 13 * 13);
    float* c3    = alloc((size_t)128 * 384 * 13 * 13);
    float* c4    = alloc((size_t)128 * 384 * 13 * 13);
    (void)ws_size; (void)in_sizes; (void)n_in; (void)out_size;

    const int NB = 16;  // batch chunk for conv1/conv2 staging

    // ---- layer 1: conv(3->96, k11 s4) + relu, pool 55->27, LRN ----
    for (int cs = 0; cs < 128; cs += NB) {
        int total = NB * 96 * 55 * 55;
        conv2d_relu_kernel<<<CDIV(total, 256), 256, 0, stream>>>(
            x + (size_t)cs * 3 * 227 * 227, w1, b1, cbuf,
            NB, 3, 227, 227, 96, 11, 4, 0, 1, 55, 55, 57.6f);
        int tp = NB * 96 * 27 * 27;
        maxpool3s2_kernel<<<CDIV(tp, 256), 256, 0, stream>>>(
            cbuf, p1 + (size_t)cs * 96 * 27 * 27, NB, 96, 55, 55, 27, 27);
    }
    lrn_inplace_kernel<<<CDIV(128 * 729, 256), 256, 0, stream>>>(p1, 128, 96, 729);

    // ---- layer 2: conv(96->256, k5 p2 g2) + relu, pool 27->13, LRN ----
    for (int cs = 0; cs < 128; cs += NB) {
        int total = NB * 256 * 27 * 27;
        conv2d_relu_kernel<<<CDIV(total, 256), 256, 0, stream>>>(
            p1 + (size_t)cs * 96 * 729, w2, b2, cbuf,
            NB, 96, 27, 27, 256, 5, 1, 2, 2, 27, 27, 1.f);
        int tp = NB * 256 * 13 * 13;
        maxpool3s2_kernel<<<CDIV(tp, 256), 256, 0, stream>>>(
            cbuf, p2 + (size_t)cs * 256 * 169, NB, 256, 27, 27, 13, 13);
    }
    lrn_inplace_kernel<<<CDIV(128 * 169, 256), 256, 0, stream>>>(p2, 128, 256, 169);

    // ---- conv3 (256->384), conv4 (384->384 g2), conv5 (384->256 g2), pool 13->6 ----
    {
        int total = 128 * 384 * 169;
        conv2d_relu_kernel<<<CDIV(total, 256), 256, 0, stream>>>(
            p2, w3, b3, c3, 128, 256, 13, 13, 384, 3, 1, 1, 1, 13, 13, 1.f);
        conv2d_relu_kernel<<<CDIV(total, 256), 256, 0, stream>>>(
            c3, w4, b4, c4, 128, 384, 13, 13, 384, 3, 1, 1, 2, 13, 13, 1.f);
        int t5 = 128 * 256 * 169;
        conv2d_relu_kernel<<<CDIV(t5, 256), 256, 0, stream>>>(
            c4, w5, b5, c3 /* reuse */, 128, 384, 13, 13, 256, 3, 1, 1, 2, 13, 13, 1.f);
        int tp = 128 * 256 * 36;
        maxpool3s2_kernel<<<CDIV(tp, 256), 256, 0, stream>>>(
            c3, feat, 128, 256, 13, 13, 6, 6);
    }

    // ---- head forward on feat (keep h1, h2 relu masks) ----
    dim3 blk(TS, TS);
    gemm_nt_kernel<<<dim3(4096 / TS, 128 / TS), blk, 0, stream>>>(feat, w6, b6, h1, 128, 4096, 9216, 1);
    gemm_nt_kernel<<<dim3(4096 / TS, 128 / TS), blk, 0, stream>>>(h1, w7, b7, h2, 128, 4096, 4096, 1);
    gemm_nt_kernel<<<dim3(CDIV(100, TS), 128 / TS), blk, 0, stream>>>(h2, wc, bc, out0, 128, 100, 4096, 0);

    // ---- analytic backward of sum(out[rows, gt]) w.r.t. feat ----
    g2m_kernel<<<CDIV(128 * 4096, 256), 256, 0, stream>>>(wc, gt, h2, g2m, 128, 4096);
    gemm_nn_kernel<<<dim3(4096 / TS, 128 / TS), blk, 0, stream>>>(g2m, w7, g1, 128, 4096, 4096);
    relumask_kernel<<<CDIV(128 * 4096, 256), 256, 0, stream>>>(g1, h1, 128 * 4096);
    gemm_nn_kernel<<<dim3(9216 / TS, 128 / TS), blk, 0, stream>>>(g1, w6, gf, 128, 9216, 4096);

    // ---- RSC spatial mask ----
    spatial_mean_kernel<<<CDIV(128 * 36, 128), 128, 0, stream>>>(gf, sm, 128, 256, 36);
    rsc_mask_kernel<<<2, 64, 0, stream>>>(sm, u, mask, 128, 36, 12);

    // ---- masked head forward ----
    maskfeat_kernel<<<CDIV(128 * 9216, 256), 256, 0, stream>>>(feat, mask, featb, 128, 9216, 36);
    gemm_nt_kernel<<<dim3(4096 / TS, 128 / TS), blk, 0, stream>>>(featb, w6, b6, h1b, 128, 4096, 9216, 1);
    gemm_nt_kernel<<<dim3(4096 / TS, 128 / TS), blk, 0, stream>>>(h1b, w7, b7, h2b, 128, 4096, 4096, 1);
    gemm_nt_kernel<<<dim3(CDIV(100, TS), 128 / TS), blk, 0, stream>>>(h2b, wc, bc, out1, 128, 100, 4096, 0);

    // ---- cv, keep threshold (round(128/3)=43), final row select ----
    cv_kernel<<<1, 128, 0, stream>>>(out0, out1, gt, cv, 128, 100);
    final_select_kernel<<<1, 128, 0, stream>>>(cv, out0, out1, flag, out, 128, 100, 43);
}

// Round 2
// 7831.330 us; speedup vs baseline: 5.6625x; 5.6625x over previous
//
#include <hip/hip_runtime.h>

#define CDIV(a,b) (((a)+(b)-1)/(b))
#define TS 16

// ============ implicit-GEMM conv: 64(cout) x 64(n*h*w) tile, 4x4/thread =======
// out = relu(bias + inscale * conv(in, wt)); wt layout [Cout][cig][K][K]
template<int KSZ, int STRIDE, int PAD>
__global__ __launch_bounds__(256) void conv_igemm(
    const float* __restrict__ in, const float* __restrict__ wt,
    const float* __restrict__ bs, float* __restrict__ out,
    int N, int Cin, int Hin, int Win, int Cout, int groups,
    int Hout, int Wout, float inscale)
{
    const int cig = Cin / groups, cog = Cout / groups;
    const int R = cig * KSZ * KSZ;
    const int HW = Hout * Wout;
    const int NSP = N * HW;
    const int g = blockIdx.z;
    const int sp0 = blockIdx.x * 64;
    const int co0 = blockIdx.y * 64;              // within group
    const int tx = threadIdx.x, ty = threadIdx.y;
    const int tid = ty * 16 + tx;

    __shared__ float Ws[16][68];
    __shared__ float Xs[16][68];
    float acc[4][4] = {};

    // ---- X-load precompute (this thread always loads spatial column sp0+xsp)
    const int xsp = tid & 63;
    const int xkk0 = tid >> 6;                    // 0..3
    const int spx = sp0 + xsp;
    const bool xvalid = spx < NSP;
    int xn = 0, xho = 0, xwo = 0;
    if (xvalid) { xn = spx / HW; int pp = spx - xn * HW; xho = pp / Wout; xwo = pp - xho * Wout; }
    const float* inb = in + ((size_t)xn * Cin + (size_t)g * cig) * Hin * Win;
    const int hi0 = xho * STRIDE - PAD, wi0 = xwo * STRIDE - PAD;

    // ---- W-load precompute
    const int wco = tid >> 2;                     // 0..63
    const int wk4 = (tid & 3) * 4;
    const bool wco_ok = (co0 + wco) < cog;
    const float* wrow = wt + (size_t)(g * cog + co0 + wco) * R;

    for (int r0 = 0; r0 < R; r0 += 16) {
        // weights -> Ws[kk][co']
        if (wco_ok && (r0 + wk4 + 3) < R) {
            float4 v = *(const float4*)(wrow + r0 + wk4);
            Ws[wk4 + 0][wco] = v.x; Ws[wk4 + 1][wco] = v.y;
            Ws[wk4 + 2][wco] = v.z; Ws[wk4 + 3][wco] = v.w;
        } else {
            #pragma unroll
            for (int q = 0; q < 4; ++q) {
                int r = r0 + wk4 + q;
                Ws[wk4 + q][wco] = (wco_ok && r < R) ? wrow[r] : 0.f;
            }
        }
        // input patches -> Xs[kk][sp']   (im2col on the fly)
        #pragma unroll
        for (int p = 0; p < 4; ++p) {
            int kk = p * 4 + xkk0;
            int r = r0 + kk;
            float v = 0.f;
            if (xvalid && r < R) {
                int ci = r / (KSZ * KSZ); int rem = r - ci * (KSZ * KSZ);
                int kh = rem / KSZ, kw = rem - kh * KSZ;
                int hi = hi0 + kh, wi = wi0 + kw;
                if ((unsigned)hi < (unsigned)Hin && (unsigned)wi < (unsigned)Win)
                    v = inb[((size_t)ci * Hin + hi) * Win + wi];
            }
            Xs[kk][xsp] = v;
        }
        __syncthreads();
        #pragma unroll
        for (int kk = 0; kk < 16; ++kk) {
            float a[4], b[4];
            *(float4*)a = *(const float4*)&Ws[kk][ty * 4];
            *(float4*)b = *(const float4*)&Xs[kk][tx * 4];
            #pragma unroll
            for (int i = 0; i < 4; ++i)
                #pragma unroll
                for (int j = 0; j < 4; ++j)
                    acc[i][j] = fmaf(a[i], b[j], acc[i][j]);
        }
        __syncthreads();
    }

    // ---- epilogue: bias + scale + relu, NCHW scatter
    #pragma unroll
    for (int j = 0; j < 4; ++j) {
        int sp = sp0 + tx * 4 + j;
        if (sp >= NSP) continue;
        int n = sp / HW; int pp = sp - n * HW;
        #pragma unroll
        for (int i = 0; i < 4; ++i) {
            int cop = co0 + ty * 4 + i;
            if (cop >= cog) continue;
            int co = g * cog + cop;
            float v = bs[co] + inscale * acc[i][j];
            out[((size_t)n * Cout + co) * HW + pp] = fmaxf(v, 0.f);
        }
    }
}

// ============ register-tiled GEMM: out[M,N] = A[M,K] @ W[N,K]^T (+bias)(+relu)
__global__ __launch_bounds__(256) void gemm64_nt(
    const float* __restrict__ A, const float* __restrict__ W,
    const float* __restrict__ bias, float* __restrict__ out,
    int M, int N, int K, int relu)
{
    const int tx = threadIdx.x, ty = threadIdx.y;
    const int tid = ty * 16 + tx;
    const int m0 = blockIdx.y * 64, n0 = blockIdx.x * 64;
    __shared__ float As[16][68], Bs[16][68];
    float acc[4][4] = {};

    const int lr = tid >> 2;            // row' / col' 0..63
    const int lk4 = (tid & 3) * 4;
    const bool arow_ok = (m0 + lr) < M;
    const bool wrow_ok = (n0 + lr) < N;
    const float* arow = A + (size_t)(m0 + lr) * K;
    const float* wrow = W + (size_t)(n0 + lr) * K;

    for (int k0 = 0; k0 < K; k0 += 16) {
        if (arow_ok && (k0 + lk4 + 3) < K) {
            float4 v = *(const float4*)(arow + k0 + lk4);
            As[lk4 + 0][lr] = v.x; As[lk4 + 1][lr] = v.y; As[lk4 + 2][lr] = v.z; As[lk4 + 3][lr] = v.w;
        } else {
            #pragma unroll
            for (int q = 0; q < 4; ++q) {
                int k = k0 + lk4 + q;
                As[lk4 + q][lr] = (arow_ok && k < K) ? arow[k] : 0.f;
            }
        }
        if (wrow_ok && (k0 + lk4 + 3) < K) {
            float4 v = *(const float4*)(wrow + k0 + lk4);
            Bs[lk4 + 0][lr] = v.x; Bs[lk4 + 1][lr] = v.y; Bs[lk4 + 2][lr] = v.z; Bs[lk4 + 3][lr] = v.w;
        } else {
            #pragma unroll
            for (int q = 0; q < 4; ++q) {
                int k = k0 + lk4 + q;
                Bs[lk4 + q][lr] = (wrow_ok && k < K) ? wrow[k] : 0.f;
            }
        }
        __syncthreads();
        #pragma unroll
        for (int kk = 0; kk < 16; ++kk) {
            float a[4], b[4];
            *(float4*)a = *(const float4*)&As[kk][ty * 4];
            *(float4*)b = *(const float4*)&Bs[kk][tx * 4];
            #pragma unroll
            for (int i = 0; i < 4; ++i)
                #pragma unroll
                for (int j = 0; j < 4; ++j)
                    acc[i][j] = fmaf(a[i], b[j], acc[i][j]);
        }
        __syncthreads();
    }
    #pragma unroll
    for (int i = 0; i < 4; ++i) {
        int row = m0 + ty * 4 + i;
        if (row >= M) continue;
        #pragma unroll
        for (int j = 0; j < 4; ++j) {
            int col = n0 + tx * 4 + j;
            if (col >= N) continue;
            float v = acc[i][j] + (bias ? bias[col] : 0.f);
            out[(size_t)row * N + col] = relu ? fmaxf(v, 0.f) : v;
        }
    }
}

// ============ register-tiled GEMM: out[M,N] = A[M,K] @ W[K,N] =================
__global__ __launch_bounds__(256) void gemm64_nn(
    const float* __restrict__ A, const float* __restrict__ W,
    float* __restrict__ out, int M, int N, int K)
{
    const int tx = threadIdx.x, ty = threadIdx.y;
    const int tid = ty * 16 + tx;
    const int m0 = blockIdx.y * 64, n0 = blockIdx.x * 64;
    __shared__ float As[16][68], Bs[16][68];
    float acc[4][4] = {};

    const int lr = tid >> 2;
    const int lk4 = (tid & 3) * 4;
    const bool arow_ok = (m0 + lr) < M;
    const float* arow = A + (size_t)(m0 + lr) * K;
    const int bkk = tid >> 4;           // 0..15
    const int bn4 = (tid & 15) * 4;

    for (int k0 = 0; k0 < K; k0 += 16) {
        if (arow_ok && (k0 + lk4 + 3) < K) {
            float4 v = *(const float4*)(arow + k0 + lk4);
            As[lk4 + 0][lr] = v.x; As[lk4 + 1][lr] = v.y; As[lk4 + 2][lr] = v.z; As[lk4 + 3][lr] = v.w;
        } else {
            #pragma unroll
            for (int q = 0; q < 4; ++q) {
                int k = k0 + lk4 + q;
                As[lk4 + q][lr] = (arow_ok && k < K) ? arow[k] : 0.f;
            }
        }
        if ((k0 + bkk) < K && (n0 + bn4 + 3) < N) {
            float4 v = *(const float4*)(W + (size_t)(k0 + bkk) * N + n0 + bn4);
            Bs[bkk][bn4 + 0] = v.x; Bs[bkk][bn4 + 1] = v.y; Bs[bkk][bn4 + 2] = v.z; Bs[bkk][bn4 + 3] = v.w;
        } else {
            #pragma unroll
            for (int q = 0; q < 4; ++q) {
                int col = n0 + bn4 + q;
                Bs[bkk][bn4 + q] = ((k0 + bkk) < K && col < N) ? W[(size_t)(k0 + bkk) * N + col] : 0.f;
            }
        }
        __syncthreads();
        #pragma unroll
        for (int kk = 0; kk < 16; ++kk) {
            float a[4], b[4];
            *(float4*)a = *(const float4*)&As[kk][ty * 4];
            *(float4*)b = *(const float4*)&Bs[kk][tx * 4];
            #pragma unroll
            for (int i = 0; i < 4; ++i)
                #pragma unroll
                for (int j = 0; j < 4; ++j)
                    acc[i][j] = fmaf(a[i], b[j], acc[i][j]);
        }
        __syncthreads();
    }
    #pragma unroll
    for (int i = 0; i < 4; ++i) {
        int row = m0 + ty * 4 + i;
        if (row >= M) continue;
        #pragma unroll
        for (int j = 0; j < 4; ++j) {
            int col = n0 + tx * 4 + j;
            if (col >= N) continue;
            out[(size_t)row * N + col] = acc[i][j];
        }
    }
}

// ---------------- maxpool 3x3 stride 2 ----------------------------------------
__global__ void maxpool3s2_kernel(const float* __restrict__ in, float* __restrict__ out,
                                  int N, int C, int Hin, int Win, int Hout, int Wout)
{
    int idx = blockIdx.x * blockDim.x + threadIdx.x;
    int total = N * C * Hout * Wout;
    if (idx >= total) return;
    int wo = idx % Wout; int t = idx / Wout;
    int ho = t % Hout; t /= Hout;
    int c = t % C; int n = t / C;
    const float* ip = in + ((size_t)n * C + c) * Hin * Win;
    int h0 = ho * 2, w0 = wo * 2;
    float m = -1e30f;
    for (int dh = 0; dh < 3; ++dh)
        for (int dw = 0; dw < 3; ++dw)
            m = fmaxf(m, ip[(h0 + dh) * Win + (w0 + dw)]);
    out[idx] = m;
}

// ---------------- LRN (n=5, alpha=1e-4, beta=0.75, k=1) in-place --------------
__global__ void lrn_inplace_kernel(float* __restrict__ x, int N, int C, int HW)
{
    int idx = blockIdx.x * blockDim.x + threadIdx.x;
    int total = N * HW;
    if (idx >= total) return;
    int p = idx % HW; int n = idx / HW;
    float* base = x + (size_t)n * C * HW + p;
    const float an = 1e-4f / 5.f;
    float r0 = 0.f, r1 = 0.f, r2, r3, r4;
    r2 = base[0];
    r3 = (C > 1) ? base[(size_t)HW] : 0.f;
    r4 = (C > 2) ? base[(size_t)2 * HW] : 0.f;
    float s = r2 * r2 + r3 * r3 + r4 * r4;
    for (int c = 0; c < C; ++c) {
        base[(size_t)c * HW] = r2 / powf(1.f + an * s, 0.75f);
        s -= r0 * r0;
        r0 = r1; r1 = r2; r2 = r3; r3 = r4;
        r4 = (c + 3 < C) ? base[(size_t)(c + 3) * HW] : 0.f;
        s += r4 * r4;
    }
}

// ---------------- backward helpers --------------------------------------------
__global__ void g2m_kernel(const float* __restrict__ wc, const int* __restrict__ gt,
                           const float* __restrict__ h2, float* __restrict__ g2m,
                           int B, int D)
{
    int idx = blockIdx.x * blockDim.x + threadIdx.x;
    if (idx >= B * D) return;
    int b = idx / D, i = idx % D;
    g2m[idx] = (h2[idx] > 0.f) ? wc[(size_t)gt[b] * D + i] : 0.f;
}

__global__ void relumask_kernel(float* __restrict__ g, const float* __restrict__ h, int n)
{
    int idx = blockIdx.x * blockDim.x + threadIdx.x;
    if (idx >= n) return;
    if (h[idx] <= 0.f) g[idx] = 0.f;
}

__global__ void spatial_mean_kernel(const float* __restrict__ gf, float* __restrict__ sm,
                                    int B, int C, int HW)
{
    int idx = blockIdx.x * blockDim.x + threadIdx.x;
    if (idx >= B * HW) return;
    int b = idx / HW, p = idx % HW;
    const float* g = gf + (size_t)b * C * HW + p;
    float s = 0.f;
    for (int c = 0; c < C; ++c) s += g[(size_t)c * HW];
    sm[idx] = s / (float)C;
}

// ---------------- RSC spatial mask (exact JAX semantics) ----------------------
__global__ void rsc_mask_kernel(const float* __restrict__ sm, const float* __restrict__ u,
                                float* __restrict__ mask, int B, int HW, int drop)
{
    int b = blockIdx.x * blockDim.x + threadIdx.x;
    if (b >= B) return;
    const float* s = sm + (size_t)b * HW;
    const float* uu = u + (size_t)b * HW;
    float th = 0.f;
    for (int p = 0; p < HW; ++p) {
        float v = s[p];
        int cg = 0, ce = 0;
        for (int q = 0; q < HW; ++q) { cg += (s[q] > v); ce += (s[q] == v); }
        if (cg <= drop && drop < cg + ce) { th = v; break; }
    }
    float sc[36];
    bool chosen[36];
    for (int p = 0; p < HW; ++p) { sc[p] = (s[p] >= th) ? uu[p] : -1.0f; chosen[p] = false; }
    for (int r = 0; r < drop; ++r) {
        int best = 0; float bv = -1e30f;
        for (int p = 0; p < HW; ++p)
            if (!chosen[p] && sc[p] > bv) { bv = sc[p]; best = p; }
        chosen[best] = true;
    }
    float* m = mask + (size_t)b * HW;
    for (int p = 0; p < HW; ++p) m[p] = chosen[p] ? 0.f : 1.f;
}

__global__ void maskfeat_kernel(const float* __restrict__ feat, const float* __restrict__ mask,
                                float* __restrict__ featb, int B, int CHW, int HW)
{
    int idx = blockIdx.x * blockDim.x + threadIdx.x;
    if (idx >= B * CHW) return;
    int b = idx / CHW, j = idx % CHW;
    featb[idx] = feat[idx] * mask[(size_t)b * HW + (j % HW)];
}

__global__ void cv_kernel(const float* __restrict__ out0, const float* __restrict__ out1,
                          const int* __restrict__ gt, float* __restrict__ cv, int B, int NCc)
{
    int b = blockIdx.x * blockDim.x + threadIdx.x;
    if (b >= B) return;
    const float* a = out0 + (size_t)b * NCc;
    const float* c = out1 + (size_t)b * NCc;
    int g = gt[b];
    float m0 = -1e30f, m1 = -1e30f;
    for (int i = 0; i < NCc; ++i) { m0 = fmaxf(m0, a[i]); m1 = fmaxf(m1, c[i]); }
    float s0 = 0.f, s1 = 0.f;
    for (int i = 0; i < NCc; ++i) { s0 += expf(a[i] - m0); s1 += expf(c[i] - m1); }
    float pb = expf(a[g] - m0) / s0;
    float pa = expf(c[g] - m1) / s1;
    cv[b] = fmaxf(pb - pa - 1e-4f, 0.f);
}

__global__ void final_select_kernel(const float* __restrict__ cv, const float* __restrict__ out0,
                                    const float* __restrict__ out1, const int* __restrict__ flag,
                                    float* __restrict__ out, int B, int NCc, int kidx)
{
    __shared__ float thfg;
    int b = threadIdx.x;
    float v = cv[b];
    int cg = 0, ce = 0;
    for (int j = 0; j < B; ++j) { float w = cv[j]; cg += (w > v); ce += (w == v); }
    if (cg <= kidx && kidx < cg + ce) thfg = v;
    __syncthreads();
    bool keep = !(v > thfg);
    if (*flag == 0) keep = true;
    const float* src = keep ? out0 : out1;
    for (int c = 0; c < NCc; ++c)
        out[(size_t)b * NCc + c] = src[(size_t)b * NCc + c];
}

// ------------------------------------------------------------------------------
extern "C" void kernel_launch(void* const* d_in, const int* in_sizes, int n_in,
                              void* d_out, int out_size, void* d_ws, size_t ws_size,
                              hipStream_t stream) {
    const float* x   = (const float*)d_in[0];
    const int*   gt  = (const int*)d_in[1];
    const float* u   = (const float*)d_in[2];
    const int*   flag= (const int*)d_in[3];
    const float* w1  = (const float*)d_in[4];  const float* b1 = (const float*)d_in[5];
    const float* w2  = (const float*)d_in[6];  const float* b2 = (const float*)d_in[7];
    const float* w3  = (const float*)d_in[8];  const float* b3 = (const float*)d_in[9];
    const float* w4  = (const float*)d_in[10]; const float* b4 = (const float*)d_in[11];
    const float* w5  = (const float*)d_in[12]; const float* b5 = (const float*)d_in[13];
    const float* w6  = (const float*)d_in[14]; const float* b6 = (const float*)d_in[15];
    const float* w7  = (const float*)d_in[16]; const float* b7 = (const float*)d_in[17];
    const float* wc  = (const float*)d_in[18]; const float* bc = (const float*)d_in[19];
    float* out = (float*)d_out;

    // ---- workspace layout (floats), ~170 MB total ----
    float* w = (float*)d_ws;
    size_t off = 0;
    auto alloc = [&](size_t n) { float* p = w + off; off += n; return p; };
    float* feat  = alloc((size_t)128 * 9216);
    float* featb = alloc((size_t)128 * 9216);
    float* h1    = alloc((size_t)128 * 4096);
    float* h2    = alloc((size_t)128 * 4096);
    float* h1b   = alloc((size_t)128 * 4096);
    float* h2b   = alloc((size_t)128 * 4096);
    float* g1    = alloc((size_t)128 * 4096);
    float* g2m   = alloc((size_t)128 * 4096);
    float* gf    = alloc((size_t)128 * 9216);
    float* out0  = alloc((size_t)128 * 100);
    float* out1  = alloc((size_t)128 * 100);
    float* sm    = alloc((size_t)128 * 36);
    float* mask  = alloc((size_t)128 * 36);
    float* cv    = alloc(128);
    float* cbuf  = alloc((size_t)16 * 96 * 55 * 55);           // conv1/conv2 chunk buffer
    float* p1    = alloc((size_t)128 * 96 * 27 * 27);
    float* p2    = alloc((size_t)128 * 256 * 13 * 13);
    float* c3    = alloc((size_t)128 * 384 * 13 * 13);
    float* c4    = alloc((size_t)128 * 384 * 13 * 13);
    (void)ws_size; (void)in_sizes; (void)n_in; (void)out_size;

    const int NB = 16;
    dim3 blk(16, 16);

    // ---- layer 1: conv(3->96, k11 s4) + relu, pool 55->27, LRN ----
    for (int cs = 0; cs < 128; cs += NB) {
        conv_igemm<11, 4, 0><<<dim3(CDIV(NB * 3025, 64), 2, 1), blk, 0, stream>>>(
            x + (size_t)cs * 3 * 227 * 227, w1, b1, cbuf,
            NB, 3, 227, 227, 96, 1, 55, 55, 57.6f);
        int tp = NB * 96 * 27 * 27;
        maxpool3s2_kernel<<<CDIV(tp, 256), 256, 0, stream>>>(
            cbuf, p1 + (size_t)cs * 96 * 27 * 27, NB, 96, 55, 55, 27, 27);
    }
    lrn_inplace_kernel<<<CDIV(128 * 729, 256), 256, 0, stream>>>(p1, 128, 96, 729);

    // ---- layer 2: conv(96->256, k5 p2 g2) + relu, pool 27->13, LRN ----
    for (int cs = 0; cs < 128; cs += NB) {
        conv_igemm<5, 1, 2><<<dim3(CDIV(NB * 729, 64), 2, 2), blk, 0, stream>>>(
            p1 + (size_t)cs * 96 * 729, w2, b2, cbuf,
            NB, 96, 27, 27, 256, 2, 27, 27, 1.f);
        int tp = NB * 256 * 13 * 13;
        maxpool3s2_kernel<<<CDIV(tp, 256), 256, 0, stream>>>(
            cbuf, p2 + (size_t)cs * 256 * 169, NB, 256, 27, 27, 13, 13);
    }
    lrn_inplace_kernel<<<CDIV(128 * 169, 256), 256, 0, stream>>>(p2, 128, 256, 169);

    // ---- conv3 (256->384), conv4 (384->384 g2), conv5 (384->256 g2), pool ----
    {
        conv_igemm<3, 1, 1><<<dim3(CDIV(128 * 169, 64), 6, 1), blk, 0, stream>>>(
            p2, w3, b3, c3, 128, 256, 13, 13, 384, 1, 13, 13, 1.f);
        conv_igemm<3, 1, 1><<<dim3(CDIV(128 * 169, 64), 3, 2), blk, 0, stream>>>(
            c3, w4, b4, c4, 128, 384, 13, 13, 384, 2, 13, 13, 1.f);
        conv_igemm<3, 1, 1><<<dim3(CDIV(128 * 169, 64), 2, 2), blk, 0, stream>>>(
            c4, w5, b5, c3 /* reuse */, 128, 384, 13, 13, 256, 2, 13, 13, 1.f);
        int tp = 128 * 256 * 36;
        maxpool3s2_kernel<<<CDIV(tp, 256), 256, 0, stream>>>(
            c3, feat, 128, 256, 13, 13, 6, 6);
    }

    // ---- head forward on feat ----
    gemm64_nt<<<dim3(64, 2), blk, 0, stream>>>(feat, w6, b6, h1, 128, 4096, 9216, 1);
    gemm64_nt<<<dim3(64, 2), blk, 0, stream>>>(h1, w7, b7, h2, 128, 4096, 4096, 1);
    gemm64_nt<<<dim3(2, 2), blk, 0, stream>>>(h2, wc, bc, out0, 128, 100, 4096, 0);

    // ---- analytic backward of sum(out[rows, gt]) w.r.t. feat ----
    g2m_kernel<<<CDIV(128 * 4096, 256), 256, 0, stream>>>(wc, gt, h2, g2m, 128, 4096);
    gemm64_nn<<<dim3(64, 2), blk, 0, stream>>>(g2m, w7, g1, 128, 4096, 4096);
    relumask_kernel<<<CDIV(128 * 4096, 256), 256, 0, stream>>>(g1, h1, 128 * 4096);
    gemm64_nn<<<dim3(144, 2), blk, 0, stream>>>(g1, w6, gf, 128, 9216, 4096);

    // ---- RSC spatial mask ----
    spatial_mean_kernel<<<CDIV(128 * 36, 128), 128, 0, stream>>>(gf, sm, 128, 256, 36);
    rsc_mask_kernel<<<2, 64, 0, stream>>>(sm, u, mask, 128, 36, 12);

    // ---- masked head forward ----
    maskfeat_kernel<<<CDIV(128 * 9216, 256), 256, 0, stream>>>(feat, mask, featb, 128, 9216, 36);
    gemm64_nt<<<dim3(64, 2), blk, 0, stream>>>(featb, w6, b6, h1b, 128, 4096, 9216, 1);
    gemm64_nt<<<dim3(64, 2), blk, 0, stream>>>(h1b, w7, b7, h2b, 128, 4096, 4096, 1);
    gemm64_nt<<<dim3(2, 2), blk, 0, stream>>>(h2b, wc, bc, out1, 128, 100, 4096, 0);

    // ---- cv, keep threshold (round(128/3)=43), final row select ----
    cv_kernel<<<1, 128, 0, stream>>>(out0, out1, gt, cv, 128, 100);
    final_select_kernel<<<1, 128, 0, stream>>>(cv, out0, out1, flag, out, 128, 100, 43);
}

// Round 3
// 5705.650 us; speedup vs baseline: 7.7721x; 1.3726x over previous
//
#include <hip/hip_runtime.h>

#define CDIV(a,b) (((a)+(b)-1)/(b))

// ============ implicit-GEMM conv: 128(cout) x 128(n*h*w) tile, 8x8/thread =====
// out = relu(bias + inscale * conv(in, wt)); wt layout [Cout][cig][K][K]
template<int KSZ, int STRIDE, int PAD>
__global__ __launch_bounds__(256, 2) void conv_igemm128(
    const float* __restrict__ in, const float* __restrict__ wt,
    const float* __restrict__ bs, float* __restrict__ out,
    int N, int Cin, int Hin, int Win, int Cout, int groups,
    int Hout, int Wout, float inscale)
{
    const int cig = Cin / groups, cog = Cout / groups;
    const int R = cig * KSZ * KSZ;
    const int HW = Hout * Wout;
    const int NSP = N * HW;
    const int g = blockIdx.z;
    const int sp0 = blockIdx.x * 128;
    const int co0 = blockIdx.y * 128;
    const int tid = threadIdx.x;

    __shared__ float Ws[16][132];
    __shared__ float Xs[16][132];
    float acc[8][8] = {};

    const int rg = tid >> 4;      // 0..15 (row group)
    const int cg = tid & 15;      // 0..15 (col group)

    // ---- W staging mapping: thread -> (co', 8 consecutive r)
    const int wco = tid >> 1;            // 0..127
    const int wrq = (tid & 1) * 8;       // 0 or 8
    const bool wok = (co0 + wco) < cog;
    const float* wrow = wt + (size_t)(g * cog + co0 + wco) * R;
    const bool wvec = ((R & 3) == 0);    // float4-safe only if R keeps 16B alignment

    // ---- X staging mapping: thread -> (sp', 8 consecutive kk)
    const int xsp = tid & 127;
    const int xk0 = (tid >> 7) * 8;      // 0 or 8
    const int spx = sp0 + xsp;
    const bool xok = spx < NSP;
    int xn = 0, xho = 0, xwo = 0;
    if (xok) { xn = spx / HW; int pp = spx - xn * HW; xho = pp / Wout; xwo = pp - xho * Wout; }
    const float* inb = in + ((size_t)xn * Cin + (size_t)g * cig) * Hin * Win;
    const int hi0 = xho * STRIDE - PAD, wi0 = xwo * STRIDE - PAD;

    for (int r0 = 0; r0 < R; r0 += 16) {
        // ---- weights -> Ws[kk][co']
        if (wvec && wok && (r0 + wrq + 7) < R) {
            float4 v0 = *(const float4*)(wrow + r0 + wrq);
            float4 v1 = *(const float4*)(wrow + r0 + wrq + 4);
            Ws[wrq + 0][wco] = v0.x; Ws[wrq + 1][wco] = v0.y;
            Ws[wrq + 2][wco] = v0.z; Ws[wrq + 3][wco] = v0.w;
            Ws[wrq + 4][wco] = v1.x; Ws[wrq + 5][wco] = v1.y;
            Ws[wrq + 6][wco] = v1.z; Ws[wrq + 7][wco] = v1.w;
        } else {
            #pragma unroll
            for (int q = 0; q < 8; ++q) {
                int r = r0 + wrq + q;
                Ws[wrq + q][wco] = (wok && r < R) ? wrow[r] : 0.f;
            }
        }
        // ---- input patches -> Xs[kk][sp'] (im2col on the fly)
        #pragma unroll
        for (int q = 0; q < 8; ++q) {
            int kk = xk0 + q;
            int r = r0 + kk;
            float v = 0.f;
            if (xok && r < R) {
                int ci = r / (KSZ * KSZ); int rem = r - ci * (KSZ * KSZ);
                int kh = rem / KSZ, kw = rem - kh * KSZ;
                int hi = hi0 + kh, wi = wi0 + kw;
                if ((unsigned)hi < (unsigned)Hin && (unsigned)wi < (unsigned)Win)
                    v = inb[((size_t)ci * Hin + hi) * Win + wi];
            }
            Xs[kk][xsp] = v;
        }
        __syncthreads();
        #pragma unroll
        for (int kk = 0; kk < 16; ++kk) {
            float a[8], b[8];
            *(float4*)&a[0] = *(const float4*)&Ws[kk][rg * 4];
            *(float4*)&a[4] = *(const float4*)&Ws[kk][64 + rg * 4];
            *(float4*)&b[0] = *(const float4*)&Xs[kk][cg * 4];
            *(float4*)&b[4] = *(const float4*)&Xs[kk][64 + cg * 4];
            #pragma unroll
            for (int i = 0; i < 8; ++i)
                #pragma unroll
                for (int j = 0; j < 8; ++j)
                    acc[i][j] = fmaf(a[i], b[j], acc[i][j]);
        }
        __syncthreads();
    }

    // ---- epilogue: bias + scale + relu, NCHW scatter
    #pragma unroll
    for (int j = 0; j < 8; ++j) {
        int sp = sp0 + (j >> 2) * 64 + cg * 4 + (j & 3);
        if (sp >= NSP) continue;
        int n = sp / HW; int pp = sp - n * HW;
        #pragma unroll
        for (int i = 0; i < 8; ++i) {
            int cop = co0 + (i >> 2) * 64 + rg * 4 + (i & 3);
            if (cop >= cog) continue;
            int co = g * cog + cop;
            float v = bs[co] + inscale * acc[i][j];
            out[((size_t)n * Cout + co) * HW + pp] = fmaxf(v, 0.f);
        }
    }
}

// ============ split-K NT GEMM: part[kz] = A[M,krange] @ W[N,krange]^T =========
__global__ __launch_bounds__(256) void gemm64_nt_k(
    const float* __restrict__ A, const float* __restrict__ W,
    float* __restrict__ part, int M, int N, int K, int kchunk)
{
    const int tx = threadIdx.x, ty = threadIdx.y;
    const int tid = ty * 16 + tx;
    const int m0 = blockIdx.y * 64, n0 = blockIdx.x * 64;
    const int kz = blockIdx.z;
    const int kbeg = kz * kchunk;
    const int kend = min(K, kbeg + kchunk);
    __shared__ float As[16][68], Bs[16][68];
    float acc[4][4] = {};

    const int lr = tid >> 2;
    const int lk4 = (tid & 3) * 4;
    const bool arow_ok = (m0 + lr) < M;
    const bool wrow_ok = (n0 + lr) < N;
    const float* arow = A + (size_t)(m0 + lr) * K;
    const float* wrow = W + (size_t)(n0 + lr) * K;

    for (int k0 = kbeg; k0 < kend; k0 += 16) {
        if (arow_ok && (k0 + lk4 + 3) < kend) {
            float4 v = *(const float4*)(arow + k0 + lk4);
            As[lk4 + 0][lr] = v.x; As[lk4 + 1][lr] = v.y; As[lk4 + 2][lr] = v.z; As[lk4 + 3][lr] = v.w;
        } else {
            #pragma unroll
            for (int q = 0; q < 4; ++q) {
                int k = k0 + lk4 + q;
                As[lk4 + q][lr] = (arow_ok && k < kend) ? arow[k] : 0.f;
            }
        }
        if (wrow_ok && (k0 + lk4 + 3) < kend) {
            float4 v = *(const float4*)(wrow + k0 + lk4);
            Bs[lk4 + 0][lr] = v.x; Bs[lk4 + 1][lr] = v.y; Bs[lk4 + 2][lr] = v.z; Bs[lk4 + 3][lr] = v.w;
        } else {
            #pragma unroll
            for (int q = 0; q < 4; ++q) {
                int k = k0 + lk4 + q;
                Bs[lk4 + q][lr] = (wrow_ok && k < kend) ? wrow[k] : 0.f;
            }
        }
        __syncthreads();
        #pragma unroll
        for (int kk = 0; kk < 16; ++kk) {
            float a[4], b[4];
            *(float4*)a = *(const float4*)&As[kk][ty * 4];
            *(float4*)b = *(const float4*)&Bs[kk][tx * 4];
            #pragma unroll
            for (int i = 0; i < 4; ++i)
                #pragma unroll
                for (int j = 0; j < 4; ++j)
                    acc[i][j] = fmaf(a[i], b[j], acc[i][j]);
        }
        __syncthreads();
    }
    float* pout = part + (size_t)kz * M * N;
    #pragma unroll
    for (int i = 0; i < 4; ++i) {
        int row = m0 + ty * 4 + i;
        if (row >= M) continue;
        #pragma unroll
        for (int j = 0; j < 4; ++j) {
            int col = n0 + tx * 4 + j;
            if (col >= N) continue;
            pout[(size_t)row * N + col] = acc[i][j];
        }
    }
}

// ============ split-K NN GEMM: part[kz] = A[M,krange] @ W[krange,N] ===========
__global__ __launch_bounds__(256) void gemm64_nn_k(
    const float* __restrict__ A, const float* __restrict__ W,
    float* __restrict__ part, int M, int N, int K, int kchunk)
{
    const int tx = threadIdx.x, ty = threadIdx.y;
    const int tid = ty * 16 + tx;
    const int m0 = blockIdx.y * 64, n0 = blockIdx.x * 64;
    const int kz = blockIdx.z;
    const int kbeg = kz * kchunk;
    const int kend = min(K, kbeg + kchunk);
    __shared__ float As[16][68], Bs[16][68];
    float acc[4][4] = {};

    const int lr = tid >> 2;
    const int lk4 = (tid & 3) * 4;
    const bool arow_ok = (m0 + lr) < M;
    const float* arow = A + (size_t)(m0 + lr) * K;
    const int bkk = tid >> 4;
    const int bn4 = (tid & 15) * 4;

    for (int k0 = kbeg; k0 < kend; k0 += 16) {
        if (arow_ok && (k0 + lk4 + 3) < kend) {
            float4 v = *(const float4*)(arow + k0 + lk4);
            As[lk4 + 0][lr] = v.x; As[lk4 + 1][lr] = v.y; As[lk4 + 2][lr] = v.z; As[lk4 + 3][lr] = v.w;
        } else {
            #pragma unroll
            for (int q = 0; q < 4; ++q) {
                int k = k0 + lk4 + q;
                As[lk4 + q][lr] = (arow_ok && k < kend) ? arow[k] : 0.f;
            }
        }
        if ((k0 + bkk) < kend && (n0 + bn4 + 3) < N) {
            float4 v = *(const float4*)(W + (size_t)(k0 + bkk) * N + n0 + bn4);
            Bs[bkk][bn4 + 0] = v.x; Bs[bkk][bn4 + 1] = v.y; Bs[bkk][bn4 + 2] = v.z; Bs[bkk][bn4 + 3] = v.w;
        } else {
            #pragma unroll
            for (int q = 0; q < 4; ++q) {
                int col = n0 + bn4 + q;
                Bs[bkk][bn4 + q] = ((k0 + bkk) < kend && col < N) ? W[(size_t)(k0 + bkk) * N + col] : 0.f;
            }
        }
        __syncthreads();
        #pragma unroll
        for (int kk = 0; kk < 16; ++kk) {
            float a[4], b[4];
            *(float4*)a = *(const float4*)&As[kk][ty * 4];
            *(float4*)b = *(const float4*)&Bs[kk][tx * 4];
            #pragma unroll
            for (int i = 0; i < 4; ++i)
                #pragma unroll
                for (int j = 0; j < 4; ++j)
                    acc[i][j] = fmaf(a[i], b[j], acc[i][j]);
        }
        __syncthreads();
    }
    float* pout = part + (size_t)kz * M * N;
    #pragma unroll
    for (int i = 0; i < 4; ++i) {
        int row = m0 + ty * 4 + i;
        if (row >= M) continue;
        #pragma unroll
        for (int j = 0; j < 4; ++j) {
            int col = n0 + tx * 4 + j;
            if (col >= N) continue;
            pout[(size_t)row * N + col] = acc[i][j];
        }
    }
}

// ---------------- split-K reduce, fused bias + relu ----------------------------
__global__ void reduce_parts(const float* __restrict__ part, const float* __restrict__ bias,
                             float* __restrict__ out, int MN, int N, int P, int relu)
{
    int idx = blockIdx.x * blockDim.x + threadIdx.x;
    if (idx >= MN) return;
    float s = 0.f;
    for (int p = 0; p < P; ++p) s += part[(size_t)p * MN + idx];
    if (bias) s += bias[idx % N];
    out[idx] = relu ? fmaxf(s, 0.f) : s;
}

// ---------------- maxpool 3x3 stride 2 ----------------------------------------
__global__ void maxpool3s2_kernel(const float* __restrict__ in, float* __restrict__ out,
                                  int N, int C, int Hin, int Win, int Hout, int Wout)
{
    int idx = blockIdx.x * blockDim.x + threadIdx.x;
    int total = N * C * Hout * Wout;
    if (idx >= total) return;
    int wo = idx % Wout; int t = idx / Wout;
    int ho = t % Hout; t /= Hout;
    int c = t % C; int n = t / C;
    const float* ip = in + ((size_t)n * C + c) * Hin * Win;
    int h0 = ho * 2, w0 = wo * 2;
    float m = -1e30f;
    for (int dh = 0; dh < 3; ++dh)
        for (int dw = 0; dw < 3; ++dw)
            m = fmaxf(m, ip[(h0 + dh) * Win + (w0 + dw)]);
    out[idx] = m;
}

// ---------------- LRN (n=5, alpha=1e-4, beta=0.75, k=1) in-place --------------
__global__ void lrn_inplace_kernel(float* __restrict__ x, int N, int C, int HW)
{
    int idx = blockIdx.x * blockDim.x + threadIdx.x;
    int total = N * HW;
    if (idx >= total) return;
    int p = idx % HW; int n = idx / HW;
    float* base = x + (size_t)n * C * HW + p;
    const float an = 1e-4f / 5.f;
    float r0 = 0.f, r1 = 0.f, r2, r3, r4;
    r2 = base[0];
    r3 = (C > 1) ? base[(size_t)HW] : 0.f;
    r4 = (C > 2) ? base[(size_t)2 * HW] : 0.f;
    float s = r2 * r2 + r3 * r3 + r4 * r4;
    for (int c = 0; c < C; ++c) {
        base[(size_t)c * HW] = r2 / powf(1.f + an * s, 0.75f);
        s -= r0 * r0;
        r0 = r1; r1 = r2; r2 = r3; r3 = r4;
        r4 = (c + 3 < C) ? base[(size_t)(c + 3) * HW] : 0.f;
        s += r4 * r4;
    }
}

// ---------------- backward helpers --------------------------------------------
__global__ void g2m_kernel(const float* __restrict__ wc, const int* __restrict__ gt,
                           const float* __restrict__ h2, float* __restrict__ g2m,
                           int B, int D)
{
    int idx = blockIdx.x * blockDim.x + threadIdx.x;
    if (idx >= B * D) return;
    int b = idx / D, i = idx % D;
    g2m[idx] = (h2[idx] > 0.f) ? wc[(size_t)gt[b] * D + i] : 0.f;
}

__global__ void relumask_kernel(float* __restrict__ g, const float* __restrict__ h, int n)
{
    int idx = blockIdx.x * blockDim.x + threadIdx.x;
    if (idx >= n) return;
    if (h[idx] <= 0.f) g[idx] = 0.f;
}

__global__ void spatial_mean_kernel(const float* __restrict__ gf, float* __restrict__ sm,
                                    int B, int C, int HW)
{
    int idx = blockIdx.x * blockDim.x + threadIdx.x;
    if (idx >= B * HW) return;
    int b = idx / HW, p = idx % HW;
    const float* g = gf + (size_t)b * C * HW + p;
    float s = 0.f;
    for (int c = 0; c < C; ++c) s += g[(size_t)c * HW];
    sm[idx] = s / (float)C;
}

// ---------------- RSC spatial mask (exact JAX semantics) ----------------------
__global__ void rsc_mask_kernel(const float* __restrict__ sm, const float* __restrict__ u,
                                float* __restrict__ mask, int B, int HW, int drop)
{
    int b = blockIdx.x * blockDim.x + threadIdx.x;
    if (b >= B) return;
    const float* s = sm + (size_t)b * HW;
    const float* uu = u + (size_t)b * HW;
    float th = 0.f;
    for (int p = 0; p < HW; ++p) {
        float v = s[p];
        int cg = 0, ce = 0;
        for (int q = 0; q < HW; ++q) { cg += (s[q] > v); ce += (s[q] == v); }
        if (cg <= drop && drop < cg + ce) { th = v; break; }
    }
    float sc[36];
    bool chosen[36];
    for (int p = 0; p < HW; ++p) { sc[p] = (s[p] >= th) ? uu[p] : -1.0f; chosen[p] = false; }
    for (int r = 0; r < drop; ++r) {
        int best = 0; float bv = -1e30f;
        for (int p = 0; p < HW; ++p)
            if (!chosen[p] && sc[p] > bv) { bv = sc[p]; best = p; }
        chosen[best] = true;
    }
    float* m = mask + (size_t)b * HW;
    for (int p = 0; p < HW; ++p) m[p] = chosen[p] ? 0.f : 1.f;
}

__global__ void maskfeat_kernel(const float* __restrict__ feat, const float* __restrict__ mask,
                                float* __restrict__ featb, int B, int CHW, int HW)
{
    int idx = blockIdx.x * blockDim.x + threadIdx.x;
    if (idx >= B * CHW) return;
    int b = idx / CHW, j = idx % CHW;
    featb[idx] = feat[idx] * mask[(size_t)b * HW + (j % HW)];
}

__global__ void cv_kernel(const float* __restrict__ out0, const float* __restrict__ out1,
                          const int* __restrict__ gt, float* __restrict__ cv, int B, int NCc)
{
    int b = blockIdx.x * blockDim.x + threadIdx.x;
    if (b >= B) return;
    const float* a = out0 + (size_t)b * NCc;
    const float* c = out1 + (size_t)b * NCc;
    int g = gt[b];
    float m0 = -1e30f, m1 = -1e30f;
    for (int i = 0; i < NCc; ++i) { m0 = fmaxf(m0, a[i]); m1 = fmaxf(m1, c[i]); }
    float s0 = 0.f, s1 = 0.f;
    for (int i = 0; i < NCc; ++i) { s0 += expf(a[i] - m0); s1 += expf(c[i] - m1); }
    float pb = expf(a[g] - m0) / s0;
    float pa = expf(c[g] - m1) / s1;
    cv[b] = fmaxf(pb - pa - 1e-4f, 0.f);
}

__global__ void final_select_kernel(const float* __restrict__ cv, const float* __restrict__ out0,
                                    const float* __restrict__ out1, const int* __restrict__ flag,
                                    float* __restrict__ out, int B, int NCc, int kidx)
{
    __shared__ float thfg;
    int b = threadIdx.x;
    float v = cv[b];
    int cg = 0, ce = 0;
    for (int j = 0; j < B; ++j) { float w = cv[j]; cg += (w > v); ce += (w == v); }
    if (cg <= kidx && kidx < cg + ce) thfg = v;
    __syncthreads();
    bool keep = !(v > thfg);
    if (*flag == 0) keep = true;
    const float* src = keep ? out0 : out1;
    for (int c = 0; c < NCc; ++c)
        out[(size_t)b * NCc + c] = src[(size_t)b * NCc + c];
}

// ------------------------------------------------------------------------------
extern "C" void kernel_launch(void* const* d_in, const int* in_sizes, int n_in,
                              void* d_out, int out_size, void* d_ws, size_t ws_size,
                              hipStream_t stream) {
    const float* x   = (const float*)d_in[0];
    const int*   gt  = (const int*)d_in[1];
    const float* u   = (const float*)d_in[2];
    const int*   flag= (const int*)d_in[3];
    const float* w1  = (const float*)d_in[4];  const float* b1 = (const float*)d_in[5];
    const float* w2  = (const float*)d_in[6];  const float* b2 = (const float*)d_in[7];
    const float* w3  = (const float*)d_in[8];  const float* b3 = (const float*)d_in[9];
    const float* w4  = (const float*)d_in[10]; const float* b4 = (const float*)d_in[11];
    const float* w5  = (const float*)d_in[12]; const float* b5 = (const float*)d_in[13];
    const float* w6  = (const float*)d_in[14]; const float* b6 = (const float*)d_in[15];
    const float* w7  = (const float*)d_in[16]; const float* b7 = (const float*)d_in[17];
    const float* wc  = (const float*)d_in[18]; const float* bc = (const float*)d_in[19];
    float* out = (float*)d_out;
    (void)ws_size; (void)in_sizes; (void)n_in; (void)out_size;

    // ---- workspace layout (floats), peak ~153.5 MB with aliasing ----
    float* w = (float*)d_ws;
    float* p1 = w;                                   // 128*96*729   = 8,957,952
    float* p2 = p1 + (size_t)8957952;                // 128*256*169  = 5,537,792
    float* Br = p2 + (size_t)5537792;                // reused region, 23,887,872
    // phase 1: conv1 chunk buffer (32*96*3025 = 9,292,800)
    float* cbuf1 = Br;
    // phase 2: conv2 full output (128*256*729 = 23,887,872)
    float* cbuf2 = Br;
    // phase 3: everything after conv2 (sums to 23,332,992 < 23,887,872)
    float* c3    = Br;                               // 128*384*169 = 8,306,688
    float* c4    = c3 + (size_t)8306688;             // 8,306,688 (later: split-K partials)
    float* feat  = c4 + (size_t)8306688;             // 1,179,648
    float* featb = feat + (size_t)1179648;
    float* h1    = featb + (size_t)1179648;          // 524,288 each
    float* h2    = h1 + (size_t)524288;
    float* h1b   = h2 + (size_t)524288;
    float* h2b   = h1b + (size_t)524288;
    float* g1    = h2b + (size_t)524288;
    float* g2m   = g1 + (size_t)524288;
    float* gf    = g2m + (size_t)524288;             // 1,179,648
    float* out0  = gf + (size_t)1179648;             // 12,800
    float* out1  = out0 + 12800;
    float* sm    = out1 + 12800;                     // 4,608
    float* mask  = sm + 4608;
    float* cv    = mask + 4608;
    float* part  = c4;                               // split-K partials (c4 dead after conv5)

    // ---- layer 1: conv(3->96, k11 s4) + relu, pool 55->27, LRN (4 chunks of 32)
    for (int cs = 0; cs < 128; cs += 32) {
        conv_igemm128<11, 4, 0><<<dim3(CDIV(32 * 3025, 128), 1, 1), 256, 0, stream>>>(
            x + (size_t)cs * 3 * 227 * 227, w1, b1, cbuf1,
            32, 3, 227, 227, 96, 1, 55, 55, 57.6f);
        maxpool3s2_kernel<<<CDIV(32 * 96 * 729, 256), 256, 0, stream>>>(
            cbuf1, p1 + (size_t)cs * 96 * 729, 32, 96, 55, 55, 27, 27);
    }
    lrn_inplace_kernel<<<CDIV(128 * 729, 256), 256, 0, stream>>>(p1, 128, 96, 729);

    // ---- layer 2: conv(96->256, k5 p2 g2) full batch, pool 27->13, LRN ----
    conv_igemm128<5, 1, 2><<<dim3(CDIV(128 * 729, 128), 1, 2), 256, 0, stream>>>(
        p1, w2, b2, cbuf2, 128, 96, 27, 27, 256, 2, 27, 27, 1.f);
    maxpool3s2_kernel<<<CDIV(128 * 256 * 169, 256), 256, 0, stream>>>(
        cbuf2, p2, 128, 256, 27, 27, 13, 13);
    lrn_inplace_kernel<<<CDIV(128 * 169, 256), 256, 0, stream>>>(p2, 128, 256, 169);

    // ---- conv3 (256->384), conv4 (384->384 g2), conv5 (384->256 g2), pool ----
    conv_igemm128<3, 1, 1><<<dim3(CDIV(128 * 169, 128), 3, 1), 256, 0, stream>>>(
        p2, w3, b3, c3, 128, 256, 13, 13, 384, 1, 13, 13, 1.f);
    conv_igemm128<3, 1, 1><<<dim3(CDIV(128 * 169, 128), 2, 2), 256, 0, stream>>>(
        c3, w4, b4, c4, 128, 384, 13, 13, 384, 2, 13, 13, 1.f);
    conv_igemm128<3, 1, 1><<<dim3(CDIV(128 * 169, 128), 1, 2), 256, 0, stream>>>(
        c4, w5, b5, c3 /* reuse */, 128, 384, 13, 13, 256, 2, 13, 13, 1.f);
    maxpool3s2_kernel<<<CDIV(128 * 256 * 36, 256), 256, 0, stream>>>(
        c3, feat, 128, 256, 13, 13, 6, 6);

    // ---- head forward on feat (split-K GEMMs, partials in `part`) ----
    dim3 blk(16, 16);
    gemm64_nt_k<<<dim3(64, 2, 8), blk, 0, stream>>>(feat, w6, part, 128, 4096, 9216, 1152);
    reduce_parts<<<CDIV(128 * 4096, 256), 256, 0, stream>>>(part, b6, h1, 128 * 4096, 4096, 8, 1);
    gemm64_nt_k<<<dim3(64, 2, 8), blk, 0, stream>>>(h1, w7, part, 128, 4096, 4096, 512);
    reduce_parts<<<CDIV(128 * 4096, 256), 256, 0, stream>>>(part, b7, h2, 128 * 4096, 4096, 8, 1);
    gemm64_nt_k<<<dim3(2, 2, 8), blk, 0, stream>>>(h2, wc, part, 128, 100, 4096, 512);
    reduce_parts<<<CDIV(128 * 100, 256), 256, 0, stream>>>(part, bc, out0, 128 * 100, 100, 8, 0);

    // ---- analytic backward of sum(out[rows, gt]) w.r.t. feat ----
    g2m_kernel<<<CDIV(128 * 4096, 256), 256, 0, stream>>>(wc, gt, h2, g2m, 128, 4096);
    gemm64_nn_k<<<dim3(64, 2, 8), blk, 0, stream>>>(g2m, w7, part, 128, 4096, 4096, 512);
    reduce_parts<<<CDIV(128 * 4096, 256), 256, 0, stream>>>(part, nullptr, g1, 128 * 4096, 4096, 8, 0);
    relumask_kernel<<<CDIV(128 * 4096, 256), 256, 0, stream>>>(g1, h1, 128 * 4096);
    gemm64_nn_k<<<dim3(144, 2, 4), blk, 0, stream>>>(g1, w6, part, 128, 9216, 4096, 1024);
    reduce_parts<<<CDIV(128 * 9216, 256), 256, 0, stream>>>(part, nullptr, gf, 128 * 9216, 9216, 4, 0);

    // ---- RSC spatial mask ----
    spatial_mean_kernel<<<CDIV(128 * 36, 128), 128, 0, stream>>>(gf, sm, 128, 256, 36);
    rsc_mask_kernel<<<2, 64, 0, stream>>>(sm, u, mask, 128, 36, 12);

    // ---- masked head forward ----
    maskfeat_kernel<<<CDIV(128 * 9216, 256), 256, 0, stream>>>(feat, mask, featb, 128, 9216, 36);
    gemm64_nt_k<<<dim3(64, 2, 8), blk, 0, stream>>>(featb, w6, part, 128, 4096, 9216, 1152);
    reduce_parts<<<CDIV(128 * 4096, 256), 256, 0, stream>>>(part, b6, h1b, 128 * 4096, 4096, 8, 1);
    gemm64_nt_k<<<dim3(64, 2, 8), blk, 0, stream>>>(h1b, w7, part, 128, 4096, 4096, 512);
    reduce_parts<<<CDIV(128 * 4096, 256), 256, 0, stream>>>(part, b7, h2b, 128 * 4096, 4096, 8, 1);
    gemm64_nt_k<<<dim3(2, 2, 8), blk, 0, stream>>>(h2b, wc, part, 128, 100, 4096, 512);
    reduce_parts<<<CDIV(128 * 100, 256), 256, 0, stream>>>(part, bc, out1, 128 * 100, 100, 8, 0);

    // ---- cv, keep threshold (round(128/3)=43), final row select ----
    cv_kernel<<<1, 128, 0, stream>>>(out0, out1, gt, cv, 128, 100);
    final_select_kernel<<<1, 128, 0, stream>>>(cv, out0, out1, flag, out, 128, 100, 43);
}